// Round 3
// baseline (1258.849 us; speedup 1.0000x reference)
//
#include <hip/hip_runtime.h>
#include <hip/hip_bf16.h>

typedef short short8 __attribute__((ext_vector_type(8)));
typedef short short4v __attribute__((ext_vector_type(4)));
typedef float f32x4 __attribute__((ext_vector_type(4)));
typedef __bf16 bf16x8 __attribute__((ext_vector_type(8)));

#define DEVI static __device__ __forceinline__

#if __has_builtin(__builtin_amdgcn_exp2f)
#define EXP2(x) __builtin_amdgcn_exp2f(x)
#else
#define EXP2(x) exp2f(x)
#endif
#if __has_builtin(__builtin_amdgcn_rcpf)
#define RCP(x) __builtin_amdgcn_rcpf(x)
#else
#define RCP(x) (1.0f / (x))
#endif

static constexpr int BB = 256, TT = 512, DIN0 = 40, HH = 128, NCLS = 7;
static constexpr int NB = 16;
static constexpr int NTHR = 512;  // 8 waves
static constexpr float L2E = 1.44269504088896f;

DEVI short f2b(float x) {
  union { __hip_bfloat16 h; short s; } u;
  u.h = __float2bfloat16(x);
  return u.s;
}

DEVI bf16x8 as_bf(short8 s) { return __builtin_bit_cast(bf16x8, s); }

// lgkm-only barrier: global loads/stores stay in flight across it.
DEVI void bar_lgkm() {
  asm volatile("s_waitcnt lgkmcnt(0)" ::: "memory");
  __builtin_amdgcn_s_barrier();
  __builtin_amdgcn_sched_barrier(0);
}

// Montgomery batched reciprocal: r[i] = 1/d[i], 1 rcp + 9 mul.
// Safe for d[i] in [1, 1+2^30] (product <= 2^122 < inf).
DEVI f32x4 inv4(f32x4 d) {
  float p1 = d[0] * d[1];
  float p2 = p1 * d[2];
  float p3 = p2 * d[3];
  float R = RCP(p3);
  f32x4 r;
  r[3] = R * p2;
  float R2 = R * d[3];
  r[2] = R2 * p1;
  float R1 = R2 * d[2];
  r[1] = R1 * d[0];
  r[0] = R1 * d[1];
  return r;
}

// One WG = (direction, 16-batch tile); 8 waves; W register-resident.
// h exchange via Hb2[buf][k-octet][bcol][8 shorts]: quarter-wave ds_read_b128
// is 256B contiguous (conflict-free); write is 2-way (free).
// L0: x fetched per-lane from global (f32), double-buffered 2 steps ahead,
//     x-projection for step s+1 computed at TOP of step s (accN ping-pong).
// L1: x = h1 staged via LDS (reg-staged 1 step ahead, XOR-swizzled), tail
//     prefill (register budget: wx needs 128 VGPRs).
template <bool IS_L0>
__global__ __launch_bounds__(NTHR, 2) void lstm3(
    const float* __restrict__ xg, const short* __restrict__ xb,
    const float* __restrict__ Wih_f, const float* __restrict__ Whh_f,
    const float* __restrict__ bias_f, const float* __restrict__ Wih_r,
    const float* __restrict__ Whh_r, const float* __restrict__ bias_r,
    short* __restrict__ h1_out, float* __restrict__ h2last) {
  constexpr int K0 = IS_L0 ? 64 : 256;    // padded x-part of K
  constexpr int DI = IS_L0 ? DIN0 : 256;  // real x dim
  constexpr int KFX = K0 / 32;            // 2 / 8
  constexpr int XB = IS_L0 ? 64 : 16384;  // L1: 2 x-buffers of 8KB

  __shared__ short Hb2[2][16][16][8];
  __shared__ char Xraw[XB];

  const int tid = threadIdx.x;
  const int w = tid >> 6;
  const int lane = tid & 63;
  const int lg = lane >> 4;
  const int bcol = lane & 15;
  const int dir = blockIdx.x & 1;
  const int b0 = (blockIdx.x >> 1) * NB;
  const int j0 = w * 16 + lg * 4;

  const float* __restrict__ Wih = dir ? Wih_r : Wih_f;
  const float* __restrict__ Whh = dir ? Whh_r : Whh_f;
  const float* __restrict__ bias = dir ? bias_r : bias_f;

  auto tmap = [&](int s) { return dir ? (TT - 1 - s) : s; };

  // ---- weights -> register fragments (A-frag: row=lane&15, k=lg*8+e) ----
  // i,f,o scaled by -log2e (sigmoid via exp2); g by +2*log2e (tanh via exp2).
  short8 wx[4][KFX];
  short8 wh[4][4];
#pragma unroll
  for (int q = 0; q < 4; ++q) {
    const float scale = (q == 2) ? (2.0f * L2E) : (-L2E);
    const int m = q * HH + w * 16 + bcol;
#pragma unroll
    for (int kk = 0; kk < KFX; ++kk) {
      short8 f;
#pragma unroll
      for (int e = 0; e < 8; ++e) {
        const int k = kk * 32 + lg * 8 + e;
        float v = (k < DI) ? Wih[(size_t)m * DI + k] : 0.0f;
        f[e] = f2b(v * scale);
      }
      wx[q][kk] = f;
    }
#pragma unroll
    for (int kk = 0; kk < 4; ++kk) {
      short8 f;
#pragma unroll
      for (int e = 0; e < 8; ++e)
        f[e] = f2b(Whh[(size_t)m * HH + kk * 32 + lg * 8 + e] * scale);
      wh[q][kk] = f;
    }
  }

  f32x4 bq[4];
#pragma unroll
  for (int q = 0; q < 4; ++q) {
    const float scale = (q == 2) ? (2.0f * L2E) : (-L2E);
#pragma unroll
    for (int r = 0; r < 4; ++r)
      bq[q][r] = bias[q * HH + w * 16 + lg * 4 + r] * scale;
  }

  // zero h buffers (h_{-1} = 0)
  for (int i = tid; i < (int)sizeof(Hb2) / 4; i += NTHR) ((int*)&Hb2[0][0][0][0])[i] = 0;
  __syncthreads();

  f32x4 cst = {0.f, 0.f, 0.f, 0.f};

  // ---- fp32 cell update; h -> Hb2[buf^1] + global ----
  auto cell = [&](f32x4& a0, f32x4& a1, f32x4& a2, f32x4& a3, int buf, int s) {
    f32x4 Ei, Ef, Eg, Eo;
#pragma unroll
    for (int r = 0; r < 4; ++r) {
      Ei[r] = EXP2(fminf(a0[r], 30.f));
      Ef[r] = EXP2(fminf(a1[r], 30.f));
      Eg[r] = EXP2(fminf(a2[r], 30.f));
      Eo[r] = EXP2(fminf(a3[r], 30.f));
    }
    const f32x4 one = {1.f, 1.f, 1.f, 1.f};
    f32x4 si = inv4(one + Ei), sf = inv4(one + Ef);
    f32x4 gd = inv4(one + Eg), so = inv4(one + Eo);
    f32x4 Ec;
#pragma unroll
    for (int r = 0; r < 4; ++r) {
      float tg = 1.f - 2.f * gd[r];
      cst[r] = sf[r] * cst[r] + si[r] * tg;
      Ec[r] = EXP2(fminf(cst[r] * (2.f * L2E), 30.f));
    }
    f32x4 cd = inv4(one + Ec);
    short4v hp;
    f32x4 hf;
#pragma unroll
    for (int r = 0; r < 4; ++r) {
      float hv = so[r] * (1.f - 2.f * cd[r]);
      hf[r] = hv;
      hp[r] = f2b(hv);
    }
    *(short4v*)&Hb2[buf ^ 1][j0 >> 3][bcol][j0 & 7] = hp;
    if constexpr (IS_L0) {
      *(short4v*)(h1_out + (((size_t)(b0 + bcol) * TT + tmap(s)) << 8) + dir * HH + j0) = hp;
    } else {
      if ((dir == 0 && s == TT - 1) || (dir == 1 && s == 0))
        *(f32x4*)(h2last + ((size_t)(b0 + bcol) << 8) + dir * HH + j0) = hf;
    }
  };

  if constexpr (IS_L0) {
    // ================= layer 0: global-direct x =================
    const float* xlane = xg + (size_t)(b0 + bcol) * TT * DI + lg * 8;
    auto ldxg = [&](f32x4* dst, int sidx) {
      int ss = (sidx < TT) ? sidx : (TT - 1);
      const float* p = xlane + (size_t)tmap(ss) * DI;
      dst[0] = *(const f32x4*)(p);
      dst[1] = *(const f32x4*)(p + 4);
      if (lg == 0) {  // k=32..39 real only for lg==0; else frag stays 0
        dst[2] = *(const f32x4*)(p + 32);
        dst[3] = *(const f32x4*)(p + 36);
      }
    };
    auto prefill = [&](f32x4* acc, const f32x4* xr) {
      short8 f0, f1;
#pragma unroll
      for (int e = 0; e < 4; ++e) {
        f0[e] = f2b(xr[0][e]);
        f0[4 + e] = f2b(xr[1][e]);
        f1[e] = f2b(xr[2][e]);
        f1[4 + e] = f2b(xr[3][e]);
      }
      bf16x8 bx0 = as_bf(f0), bx1 = as_bf(f1);
#pragma unroll
      for (int q = 0; q < 4; ++q) {
        acc[q] = __builtin_amdgcn_mfma_f32_16x16x32_bf16(as_bf(wx[q][0]), bx0, bq[q], 0, 0, 0);
        acc[q] = __builtin_amdgcn_mfma_f32_16x16x32_bf16(as_bf(wx[q][1]), bx1, acc[q], 0, 0, 0);
      }
    };
    auto step = [&](int s, int buf, f32x4* acc, f32x4* accN, f32x4* xR) {
      prefill(accN, xR);  // acc for s+1 from x(s+1) (off recurrent chain)
#pragma unroll
      for (int kk = 0; kk < 4; ++kk) {
        bf16x8 bh = as_bf(*(const short8*)&Hb2[buf][kk * 4 + lg][bcol][0]);
#pragma unroll
        for (int q = 0; q < 4; ++q)
          acc[q] = __builtin_amdgcn_mfma_f32_16x16x32_bf16(as_bf(wh[q][kk]), bh, acc[q], 0, 0, 0);
      }
      cell(acc[0], acc[1], acc[2], acc[3], buf, s);
      ldxg(xR, s + 3);  // background reload, 2 steps of slack
      bar_lgkm();
    };

    const f32x4 z = {0.f, 0.f, 0.f, 0.f};
    f32x4 xP[4] = {z, z, z, z}, xA[4] = {z, z, z, z}, xB[4] = {z, z, z, z};
    ldxg(xP, 0);
    ldxg(xA, 1);
    ldxg(xB, 2);
    f32x4 accA[4], accB[4];
    prefill(accA, xP);

    for (int s = 0; s < TT; s += 2) {
      step(s, 0, accA, accB, xA);
      step(s + 1, 1, accB, accA, xB);
    }
  } else {
    // ================= layer 1: LDS-staged x (= h1) =================
    const int xr1 = tid >> 5;  // staging batch row
    const int xcb = ((tid << 4) ^ (((tid >> 5) & 7) << 4)) & 511;  // swizzled src byte
    auto ldx = [&](int p, int kk) -> short8 {  // B-frag read, XOR-swizzled
      int byte = ((bcol << 9) + (kk << 6) + (lg << 4)) ^ ((bcol & 7) << 4);
      return *(const short8*)(Xraw + p * 8192 + byte);
    };
    auto ldg = [&](int sidx) -> short8 {
      int ss = (sidx < TT) ? sidx : (TT - 1);
      return *(const short8*)((const char*)xb + ((size_t)(b0 + xr1) * TT + tmap(ss)) * 512 + xcb);
    };

    // prologue: X[0]=x(0), X[1]=x(1); xstage=x(2)
    {
      short8 v0 = ldg(0), v1 = ldg(1);
      *(short8*)(Xraw + tid * 16) = v0;
      *(short8*)(Xraw + 8192 + tid * 16) = v1;
    }
    short8 xstage = ldg(2);
    __syncthreads();

    f32x4 acc[4];
#pragma unroll
    for (int q = 0; q < 4; ++q) acc[q] = bq[q];
#pragma unroll
    for (int kk = 0; kk < 8; ++kk) {
      bf16x8 bx = as_bf(ldx(0, kk));
#pragma unroll
      for (int q = 0; q < 4; ++q)
        acc[q] = __builtin_amdgcn_mfma_f32_16x16x32_bf16(as_bf(wx[q][kk]), bx, acc[q], 0, 0, 0);
    }
    bar_lgkm();  // X[0] readers done before step0 overwrites it

    auto step = [&](int s, int buf) {
      // stage x(s+2) (loaded one step ago) into X[buf]; issue x(s+3)
      *(short8*)(Xraw + buf * 8192 + tid * 16) = xstage;
      xstage = ldg(s + 3);
#pragma unroll
      for (int kk = 0; kk < 4; ++kk) {
        bf16x8 bh = as_bf(*(const short8*)&Hb2[buf][kk * 4 + lg][bcol][0]);
#pragma unroll
        for (int q = 0; q < 4; ++q)
          acc[q] = __builtin_amdgcn_mfma_f32_16x16x32_bf16(as_bf(wh[q][kk]), bh, acc[q], 0, 0, 0);
      }
      cell(acc[0], acc[1], acc[2], acc[3], buf, s);
      // tail prefill for s+1 from X[buf^1] = x(s+1)
#pragma unroll
      for (int q = 0; q < 4; ++q) acc[q] = bq[q];
#pragma unroll
      for (int kk = 0; kk < 8; ++kk) {
        bf16x8 bx = as_bf(ldx(buf ^ 1, kk));
#pragma unroll
        for (int q = 0; q < 4; ++q)
          acc[q] = __builtin_amdgcn_mfma_f32_16x16x32_bf16(as_bf(wx[q][kk]), bx, acc[q], 0, 0, 0);
      }
      bar_lgkm();
    };

    for (int s = 0; s < TT; s += 2) {
      step(s, 0);
      step(s + 1, 1);
    }
  }
}

__global__ void fc_kernel(const float* __restrict__ h2last,
                          const float* __restrict__ fcw,
                          const float* __restrict__ fcb,
                          float* __restrict__ out) {
  const int gid = blockIdx.x * blockDim.x + threadIdx.x;
  if (gid >= BB * NCLS) return;
  const int b = gid / NCLS, n = gid % NCLS;
  const float* hp = h2last + (size_t)b * 256;
  const float* wp = fcw + (size_t)n * 256;
  float s = fcb[n];
#pragma unroll 8
  for (int j = 0; j < 256; ++j) s = fmaf(hp[j], wp[j], s);
  out[gid] = s;
}

extern "C" void kernel_launch(void* const* d_in, const int* in_sizes, int n_in,
                              void* d_out, int out_size, void* d_ws, size_t ws_size,
                              hipStream_t stream) {
  const float* x     = (const float*)d_in[0];
  const float* Wih0f = (const float*)d_in[1];
  const float* Whh0f = (const float*)d_in[2];
  const float* b0f   = (const float*)d_in[3];
  const float* Wih0r = (const float*)d_in[4];
  const float* Whh0r = (const float*)d_in[5];
  const float* b0r   = (const float*)d_in[6];
  const float* Wih1f = (const float*)d_in[7];
  const float* Whh1f = (const float*)d_in[8];
  const float* b1f   = (const float*)d_in[9];
  const float* Wih1r = (const float*)d_in[10];
  const float* Whh1r = (const float*)d_in[11];
  const float* b1r   = (const float*)d_in[12];
  const float* fcw   = (const float*)d_in[13];
  const float* fcb   = (const float*)d_in[14];

  short* h1 = (short*)d_ws;                                           // [B][T][256] bf16, 64 MB
  float* h2last = (float*)((char*)d_ws + (size_t)BB * TT * 256 * 2);  // [B][256] f32

  lstm3<true><<<dim3(32), dim3(NTHR), 0, stream>>>(
      x, nullptr, Wih0f, Whh0f, b0f, Wih0r, Whh0r, b0r, h1, nullptr);
  lstm3<false><<<dim3(32), dim3(NTHR), 0, stream>>>(
      nullptr, h1, Wih1f, Whh1f, b1f, Wih1r, Whh1r, b1r, nullptr, h2last);
  fc_kernel<<<dim3((BB * NCLS + 255) / 256), dim3(256), 0, stream>>>(
      h2last, fcw, fcb, (float*)d_out);
}